// Round 7
// baseline (101.375 us; speedup 1.0000x reference)
//
#include <hip/hip_runtime.h>

// Le-ADMM reduction: state resets each iteration => output is one linear
// circular filter: out = crop_shift( IFFT2( K . FFT2(pad(x)) ) ),
// K = mu1[4]/((1+1e-6)*FH*FW) * conj(Hp) / (1e-6|Hp|^2 + 1e-5*PsiTPsi + 4e-5).
// Pairs packed z = x_a + i*x_b (K Hermitian => both results real).
//
// R6: k_col_fused refactored to 5 passes / 4 barriers via high radices:
// fwd 1080 = 10*12*9, inv = 9*12*10; the radix-9 fwd-final and radix-9
// inv-first share LDS slot set (stride 120) -> fused register pass
// (dft9 fwd -> *K -> dft9 inv). LDS round-trips 6->4, barriers 6->4.
// Keeps: R5 pair-per-thread float4 LDS; R3 XCD-chunked swizzle; stage-1
// from global zero-pad specialized; final stage fused with crop-store.
// Bank conflicts measured at 0.02% of cycles -- not a factor.

#define PI2 6.2831853071795864f

__device__ __forceinline__ float2 cadd(float2 a, float2 b){ return make_float2(a.x+b.x, a.y+b.y); }
__device__ __forceinline__ float2 csub(float2 a, float2 b){ return make_float2(a.x-b.x, a.y-b.y); }
__device__ __forceinline__ float2 cmul(float2 a, float2 b){ return make_float2(a.x*b.x - a.y*b.y, a.x*b.y + a.y*b.x); }
__device__ __forceinline__ float4 pk(float2 a, float2 b){ return make_float4(a.x,a.y,b.x,b.y); }

// Row kernels: pad +1 per 16 (b64 access).
__device__ __forceinline__ int IDX(int a){ return a + (a >> 4); }
#define IDXSZ(n) ((n) + ((n) >> 4))
// Column kernels: pad +2 per 32 (keeps even->even so float4 stays aligned).
__device__ __forceinline__ int IDXP(int a){ return a + ((a >> 5) << 1); }
#define IDXPSZ(n) ((n) + (((n) >> 5) << 1) + 4)

// Pair load/store: both columns at per-col position pos.
__device__ __forceinline__ void ldp(const float2* __restrict__ b, int pos,
                                    float2& v0, float2& v1){
    const float4 t = *(const float4*)&b[IDXP(2*pos)];
    v0 = make_float2(t.x,t.y); v1 = make_float2(t.z,t.w);
}
__device__ __forceinline__ void stp(float2* __restrict__ b, int pos,
                                    float2 v0, float2 v1){
    *(float4*)&b[IDXP(2*pos)] = pk(v0, v1);
}

template<int DIR>
__device__ __forceinline__ void dft3(float2 x0, float2 x1, float2 x2,
                                     float2& y0, float2& y1, float2& y2)
{
    constexpr float s3 = (float)DIR * 0.8660254037844386f;
    float2 t = cadd(x1, x2), u = csub(x1, x2);
    float2 m = make_float2(x0.x - 0.5f*t.x, x0.y - 0.5f*t.y);
    float2 iu = make_float2(-s3*u.y, s3*u.x);
    y0 = cadd(x0, t); y1 = cadd(m, iu); y2 = csub(m, iu);
}

template<int DIR>
__device__ __forceinline__ void dft4(float2 a0, float2 a1, float2 a2, float2 a3,
                                     float2& b0, float2& b1, float2& b2, float2& b3)
{
    float2 t0 = cadd(a0,a2), t1 = csub(a0,a2), t2 = cadd(a1,a3), t3 = csub(a1,a3);
    float2 j3 = make_float2(-(float)DIR*t3.y, (float)DIR*t3.x);
    b0 = cadd(t0,t2); b2 = csub(t0,t2); b1 = cadd(t1,j3); b3 = csub(t1,j3);
}

template<int DIR>
__device__ __forceinline__ void dft6(const float2 a[6], float2 b[6])
{
    float2 e0,e1,e2,o0,o1,o2;
    dft3<DIR>(a[0],a[2],a[4], e0,e1,e2);
    dft3<DIR>(a[1],a[3],a[5], o0,o1,o2);
    constexpr float s3 = (float)DIR * 0.8660254037844386f;
    float2 w1 = make_float2( 0.5f, s3);
    float2 w2 = make_float2(-0.5f, s3);
    float2 t1 = cmul(w1,o1), t2 = cmul(w2,o2);
    b[0]=cadd(e0,o0); b[3]=csub(e0,o0);
    b[1]=cadd(e1,t1); b[4]=csub(e1,t1);
    b[2]=cadd(e2,t2); b[5]=csub(e2,t2);
}

template<int DIR>
__device__ __forceinline__ void dft8(const float2 a[8], float2 b[8])
{
    float2 e0,e1,e2,e3,o0,o1,o2,o3;
    dft4<DIR>(a[0],a[2],a[4],a[6], e0,e1,e2,e3);
    dft4<DIR>(a[1],a[3],a[5],a[7], o0,o1,o2,o3);
    constexpr float c = 0.70710678118654752f;
    float2 w1 = make_float2( c, (float)DIR*c);
    float2 w3 = make_float2(-c, (float)DIR*c);
    float2 t1 = cmul(w1,o1);
    float2 t2 = make_float2(-(float)DIR*o2.y, (float)DIR*o2.x);
    float2 t3 = cmul(w3,o3);
    b[0]=cadd(e0,o0); b[4]=csub(e0,o0);
    b[1]=cadd(e1,t1); b[5]=csub(e1,t1);
    b[2]=cadd(e2,t2); b[6]=csub(e2,t2);
    b[3]=cadd(e3,t3); b[7]=csub(e3,t3);
}

template<int DIR>
__device__ __forceinline__ void dft5(const float2 a[5], float2 b[5])
{
    constexpr float C1 = 0.30901699437494742f, S1c = 0.9510565162951535f;
    constexpr float C2 = -0.8090169943749475f, S2c = 0.5877852522924731f;
    float2 t1 = cadd(a[1],a[4]), t2 = cadd(a[2],a[3]), d1 = csub(a[1],a[4]), d2 = csub(a[2],a[3]);
    float2 m1 = make_float2(a[0].x + C1*t1.x + C2*t2.x, a[0].y + C1*t1.y + C2*t2.y);
    float2 m2 = make_float2(a[0].x + C2*t1.x + C1*t2.x, a[0].y + C2*t1.y + C1*t2.y);
    float2 e1 = make_float2(S1c*d1.x + S2c*d2.x, S1c*d1.y + S2c*d2.y);
    float2 e2 = make_float2(S2c*d1.x - S1c*d2.x, S2c*d1.y - S1c*d2.y);
    float2 ie1 = make_float2(-(float)DIR*e1.y, (float)DIR*e1.x);
    float2 ie2 = make_float2(-(float)DIR*e2.y, (float)DIR*e2.x);
    b[0] = make_float2(a[0].x + t1.x + t2.x, a[0].y + t1.y + t2.y);
    b[1] = cadd(m1, ie1); b[4] = csub(m1, ie1);
    b[2] = cadd(m2, ie2); b[3] = csub(m2, ie2);
}

// dft9: 9 = 3x3. C_r = dft3(a_r,a_{r+3},a_{r+6}); d_r[m] = W9^{rm} C_r[m];
// (X[m],X[m+3],X[m+6]) = dft3_r(d_0[m],d_1[m],d_2[m]).
template<int DIR>
__device__ __forceinline__ void dft9(const float2 a[9], float2 b[9])
{
    float2 C0[3], C1[3], C2[3];
    dft3<DIR>(a[0],a[3],a[6], C0[0],C0[1],C0[2]);
    dft3<DIR>(a[1],a[4],a[7], C1[0],C1[1],C1[2]);
    dft3<DIR>(a[2],a[5],a[8], C2[0],C2[1],C2[2]);
    const float2 w91 = make_float2(0.7660444431189780f, (float)DIR*0.6427876096865393f);
    const float2 w92 = make_float2(0.1736481776669304f, (float)DIR*0.9848077530122081f);
    const float2 w94 = make_float2(-0.9396926207859084f, (float)DIR*0.3420201433256687f);
    C1[1]=cmul(C1[1],w91); C1[2]=cmul(C1[2],w92);
    C2[1]=cmul(C2[1],w92); C2[2]=cmul(C2[2],w94);
    dft3<DIR>(C0[0],C1[0],C2[0], b[0],b[3],b[6]);
    dft3<DIR>(C0[1],C1[1],C2[1], b[1],b[4],b[7]);
    dft3<DIR>(C0[2],C1[2],C2[2], b[2],b[5],b[8]);
}

// dft10: even/odd split into two dft5 + constant-twiddle combine.
template<int DIR>
__device__ __forceinline__ void dft10(const float2 a[10], float2 b[10])
{
    float2 ae[5] = {a[0],a[2],a[4],a[6],a[8]};
    float2 ao[5] = {a[1],a[3],a[5],a[7],a[9]};
    float2 E[5], O[5];
    dft5<DIR>(ae, E); dft5<DIR>(ao, O);
    const float2 w1 = make_float2( 0.8090169943749475f, (float)DIR*0.5877852522924731f);
    const float2 w2 = make_float2( 0.3090169943749474f, (float)DIR*0.9510565162951535f);
    const float2 w3 = make_float2(-0.3090169943749474f, (float)DIR*0.9510565162951535f);
    const float2 w4 = make_float2(-0.8090169943749475f, (float)DIR*0.5877852522924731f);
    float2 t1 = cmul(O[1],w1), t2 = cmul(O[2],w2), t3 = cmul(O[3],w3), t4 = cmul(O[4],w4);
    b[0]=cadd(E[0],O[0]); b[5]=csub(E[0],O[0]);
    b[1]=cadd(E[1],t1);   b[6]=csub(E[1],t1);
    b[2]=cadd(E[2],t2);   b[7]=csub(E[2],t2);
    b[3]=cadd(E[3],t3);   b[8]=csub(E[3],t3);
    b[4]=cadd(E[4],t4);   b[9]=csub(E[4],t4);
}

// dft12: 12 = 4x3. C_r = dft4(a_r,a_{r+3},a_{r+6},a_{r+9}); d_r[m] = W12^{rm}
// C_r[m]; (X[m],X[m+4],X[m+8]) = dft3_r(d_0[m],d_1[m],d_2[m]).
template<int DIR>
__device__ __forceinline__ void dft12(const float2 a[12], float2 b[12])
{
    float2 C0[4], C1[4], C2[4];
    dft4<DIR>(a[0],a[3],a[6],a[9],  C0[0],C0[1],C0[2],C0[3]);
    dft4<DIR>(a[1],a[4],a[7],a[10], C1[0],C1[1],C1[2],C1[3]);
    dft4<DIR>(a[2],a[5],a[8],a[11], C2[0],C2[1],C2[2],C2[3]);
    const float2 w121 = make_float2(0.8660254037844386f, (float)DIR*0.5f);
    const float2 w122 = make_float2(0.5f, (float)DIR*0.8660254037844386f);
    const float2 w124 = make_float2(-0.5f, (float)DIR*0.8660254037844386f);
    C1[1]=cmul(C1[1],w121); C1[2]=cmul(C1[2],w122);
    C1[3]=make_float2(-(float)DIR*C1[3].y, (float)DIR*C1[3].x);   // *W12^3 = (0,DIR)
    C2[1]=cmul(C2[1],w122); C2[2]=cmul(C2[2],w124);
    C2[3]=make_float2(-C2[3].x, -C2[3].y);                        // *W12^6 = -1
    dft3<DIR>(C0[0],C1[0],C2[0], b[0],b[4],b[8]);
    dft3<DIR>(C0[1],C1[1],C2[1], b[1],b[5],b[9]);
    dft3<DIR>(C0[2],C1[2],C2[2], b[2],b[6],b[10]);
    dft3<DIR>(C0[3],C1[3],C2[3], b[3],b[7],b[11]);
}

// Generic middle Stockham stage (rows; R = 6 or 8), LDS -> LDS, b64 slots.
template<int DIR, int R, int NCUR, int S>
__device__ __forceinline__ void mid_stage(const float2* __restrict__ src,
                                          float2* __restrict__ dst, int tid)
{
    constexpr int M  = NCUR / R;
    constexpr int NB = M * S;
    constexpr float STEP = (float)DIR * PI2 / (float)NCUR;
    for (int i = tid; i < NB; i += 256) {
        const int p = i / S;
        float2 a[R], b[R];
        #pragma unroll
        for (int t = 0; t < R; ++t) a[t] = src[IDX(i + S*M*t)];
        if constexpr (R == 6) dft6<DIR>(a,b); else dft8<DIR>(a,b);
        float sv, cv; __sincosf(STEP * (float)p, &sv, &cv);
        float2 w1 = make_float2(cv, sv), w = w1;
        b[1] = cmul(b[1], w);
        #pragma unroll
        for (int u = 2; u < R; ++u) { w = cmul(w, w1); b[u] = cmul(b[u], w); }
        const int ob = (i - p*S) + S*(R*p);
        #pragma unroll
        for (int u = 0; u < R; ++u) dst[IDX(ob + S*u)] = b[u];
    }
}

// Column middle stage (K2 path), pair-per-thread (R=6).
template<int DIR, int NCUR, int SC>
__device__ __forceinline__ void mid_pair(const float2* __restrict__ src,
                                         float2* __restrict__ dst, int tid)
{
    constexpr int NB = 180;
    constexpr float STEP = (float)DIR * PI2 / (float)NCUR;
    for (int ic = tid; ic < NB; ic += 256) {
        const int p = ic / SC;
        float2 a0[6], a1[6], b0[6], b1[6];
        #pragma unroll
        for (int t = 0; t < 6; ++t) ldp(src, ic + NB*t, a0[t], a1[t]);
        dft6<DIR>(a0,b0); dft6<DIR>(a1,b1);
        float sv, cv; __sincosf(STEP*(float)p, &sv, &cv);
        float2 w1 = make_float2(cv,sv), w = w1;
        b0[1]=cmul(b0[1],w); b1[1]=cmul(b1[1],w);
        #pragma unroll
        for (int u = 2; u < 6; ++u){ w = cmul(w,w1); b0[u]=cmul(b0[u],w); b1[u]=cmul(b1[u],w); }
        const int ob = (ic - p*SC) + SC*6*p;
        #pragma unroll
        for (int u = 0; u < 6; ++u) stp(dst, ob + SC*u, b0[u], b1[u]);
    }
}

// Column middle stage radix-12, pair-per-thread. NB = (NCUR/12)*SC = 90.
template<int DIR, int NCUR, int SC>
__device__ __forceinline__ void mid12_pair(const float2* __restrict__ src,
                                           float2* __restrict__ dst, int tid)
{
    constexpr int NB = (NCUR/12)*SC;   // 90
    constexpr float STEP = (float)DIR * PI2 / (float)NCUR;
    for (int ic = tid; ic < NB; ic += 256) {
        const int p = ic / SC;
        float2 a0[12], a1[12], b0[12], b1[12];
        #pragma unroll
        for (int t = 0; t < 12; ++t) ldp(src, ic + NB*t, a0[t], a1[t]);
        dft12<DIR>(a0,b0); dft12<DIR>(a1,b1);
        float sv, cv; __sincosf(STEP*(float)p, &sv, &cv);
        float2 w1 = make_float2(cv,sv), w = w1;
        b0[1]=cmul(b0[1],w); b1[1]=cmul(b1[1],w);
        #pragma unroll
        for (int u = 2; u < 12; ++u){ w = cmul(w,w1); b0[u]=cmul(b0[u],w); b1[u]=cmul(b1[u],w); }
        const int ob = (ic - p*SC) + SC*12*p;
        #pragma unroll
        for (int u = 0; u < 12; ++u) stp(dst, ob + SC*u, b0[u], b1[u]);
    }
}

// K2 path: column stage 1 (radix-6, SC=1, DIR=-1) from global, pair/thread.
__device__ __forceinline__ void col_s1_fwd_pair(const float2* __restrict__ g, int c0,
                                                float2* __restrict__ bA, int tid)
{
    constexpr float STEP = -PI2 / 1080.0f;
    const float2 z = make_float2(0.f,0.f);
    const float4* gc = (const float4*)(g + c0);
    for (int p = tid; p < 180; p += 256) {
        float2 a0[6], a1[6], b0[6], b1[6];
        a0[0]=a0[5]=a1[0]=a1[5]=z;
        if (p >= 90) { float4 t = gc[(p-90)*960]; a0[1]=make_float2(t.x,t.y); a1[1]=make_float2(t.z,t.w); }
        else         { a0[1]=a1[1]=z; }
        { float4 t = gc[(p+90)*960];  a0[2]=make_float2(t.x,t.y); a1[2]=make_float2(t.z,t.w); }
        { float4 t = gc[(p+270)*960]; a0[3]=make_float2(t.x,t.y); a1[3]=make_float2(t.z,t.w); }
        if (p < 90)  { float4 t = gc[(p+450)*960]; a0[4]=make_float2(t.x,t.y); a1[4]=make_float2(t.z,t.w); }
        else         { a0[4]=a1[4]=z; }
        dft6<-1>(a0,b0); dft6<-1>(a1,b1);
        float sv, cv; __sincosf(STEP*(float)p, &sv, &cv);
        float2 w1 = make_float2(cv,sv), w = w1;
        b0[1]=cmul(b0[1],w); b1[1]=cmul(b1[1],w);
        #pragma unroll
        for (int u = 2; u < 6; ++u){ w = cmul(w,w1); b0[u]=cmul(b0[u],w); b1[u]=cmul(b1[u],w); }
        #pragma unroll
        for (int u = 0; u < 6; ++u) stp(bA, 6*p + u, b0[u], b1[u]);
    }
}

// K4 stage 1: radix-10, SC=1, DIR=-1, from global, pair-per-thread.
// Samples p+108t; nonzero rows 270..809 -> a[3..6] always, a[2] if p>=54,
// a[7] if p<54 (global row = p+108t-270).
__device__ __forceinline__ void col_s1_fwd10_pair(const float2* __restrict__ g, int c0,
                                                  float2* __restrict__ bA, int tid)
{
    constexpr float STEP = -PI2 / 1080.0f;
    const float2 z = make_float2(0.f,0.f);
    const float4* gc = (const float4*)(g + c0);
    for (int p = tid; p < 108; p += 256) {
        float2 a0[10], a1[10], b0[10], b1[10];
        a0[0]=a0[1]=a0[8]=a0[9]=z; a1[0]=a1[1]=a1[8]=a1[9]=z;
        if (p >= 54) { float4 t = gc[(p-54)*960]; a0[2]=make_float2(t.x,t.y); a1[2]=make_float2(t.z,t.w); }
        else         { a0[2]=a1[2]=z; }
        { float4 t = gc[(p+54)*960];  a0[3]=make_float2(t.x,t.y); a1[3]=make_float2(t.z,t.w); }
        { float4 t = gc[(p+162)*960]; a0[4]=make_float2(t.x,t.y); a1[4]=make_float2(t.z,t.w); }
        { float4 t = gc[(p+270)*960]; a0[5]=make_float2(t.x,t.y); a1[5]=make_float2(t.z,t.w); }
        { float4 t = gc[(p+378)*960]; a0[6]=make_float2(t.x,t.y); a1[6]=make_float2(t.z,t.w); }
        if (p < 54)  { float4 t = gc[(p+486)*960]; a0[7]=make_float2(t.x,t.y); a1[7]=make_float2(t.z,t.w); }
        else         { a0[7]=a1[7]=z; }
        dft10<-1>(a0,b0); dft10<-1>(a1,b1);
        float sv, cv; __sincosf(STEP*(float)p, &sv, &cv);
        float2 w1 = make_float2(cv,sv), w = w1;
        b0[1]=cmul(b0[1],w); b1[1]=cmul(b1[1],w);
        #pragma unroll
        for (int u = 2; u < 10; ++u){ w = cmul(w,w1); b0[u]=cmul(b0[u],w); b1[u]=cmul(b1[u],w); }
        #pragma unroll
        for (int u = 0; u < 10; ++u) stp(bA, 10*p + u, b0[u], b1[u]);
    }
}

// K4 fused center: fwd-final radix-9 (p=0, twiddle-free; spectrum k = q+120u)
// -> *K -> inverse-first radix-9 (NCUR=1080, S=1, twiddle e^{+2pi i q u/1080})
// -> scatter to colpos 9q+u.
__device__ __forceinline__ void fused9K9_pair(const float2* __restrict__ src,
                                              float2* __restrict__ dst,
                                              const float4* __restrict__ KI,
                                              int cpair, int tid)
{
    constexpr float STEP = PI2 / 1080.0f;
    const float4* Kc = KI + cpair*1080;
    for (int q = tid; q < 120; q += 256) {
        float2 a0[9], a1[9], s0[9], s1[9], d0[9], d1[9];
        #pragma unroll
        for (int u = 0; u < 9; ++u) ldp(src, q + 120*u, a0[u], a1[u]);
        dft9<-1>(a0,s0); dft9<-1>(a1,s1);
        #pragma unroll
        for (int u = 0; u < 9; ++u) {
            float4 kk = Kc[q + 120*u];
            s0[u] = cmul(s0[u], make_float2(kk.x,kk.y));
            s1[u] = cmul(s1[u], make_float2(kk.z,kk.w));
        }
        dft9<1>(s0,d0); dft9<1>(s1,d1);
        float sv, cv; __sincosf(STEP*(float)q, &sv, &cv);
        float2 w1 = make_float2(cv,sv), w = w1;
        d0[1]=cmul(d0[1],w); d1[1]=cmul(d1[1],w);
        #pragma unroll
        for (int u = 2; u < 9; ++u){ w = cmul(w,w1); d0[u]=cmul(d0[u],w); d1[u]=cmul(d1[u],w); }
        #pragma unroll
        for (int u = 0; u < 9; ++u) stp(dst, 9*q + u, d0[u], d1[u]);
    }
}

// K4 inverse final radix-10 (S=108, p=0, twiddle-free) fused with crop:
// n = q+108u; keep n<270 (ir=n+270): u=0,1, u=2 if q<54; keep n>=810
// (ir=n-810): u=7 if q>=54, u=8,9. Global float4 stores.
__device__ __forceinline__ void fin10_crop_pair(const float2* __restrict__ src,
                                                float2* __restrict__ Zp,
                                                int c0, int tid)
{
    float4* gc = (float4*)(Zp + c0);
    for (int q = tid; q < 108; q += 256) {
        float2 a0[10], a1[10], b0[10], b1[10];
        #pragma unroll
        for (int u = 0; u < 10; ++u) ldp(src, q + 108*u, a0[u], a1[u]);
        dft10<1>(a0,b0); dft10<1>(a1,b1);
        gc[(q+270)*960] = pk(b0[0], b1[0]);
        gc[(q+378)*960] = pk(b0[1], b1[1]);
        if (q < 54)  gc[(q+486)*960] = pk(b0[2], b1[2]);
        if (q >= 54) gc[(q-54)*960]  = pk(b0[7], b1[7]);
        gc[(q+54)*960]  = pk(b0[8], b1[8]);
        gc[(q+162)*960] = pk(b0[9], b1[9]);
    }
}

// ---------------- row (1920 = 8*8*6*5) pieces ----------------

template<bool HASB>
__device__ __forceinline__ void row_s1_fwd(const float* __restrict__ xa,
                                           const float* __restrict__ xb,
                                           float2* __restrict__ bA, int tid)
{
    constexpr float STEP = -PI2 / 1920.0f;
    const float2 z = make_float2(0.f,0.f);
    for (int p = tid; p < 240; p += 256) {
        float2 a[8], b[8];
        a[0]=z; a[1]=z; a[6]=z; a[7]=z;
        a[2] = make_float2(xa[p],     HASB ? xb[p]     : 0.f);
        a[3] = make_float2(xa[p+240], HASB ? xb[p+240] : 0.f);
        a[4] = make_float2(xa[p+480], HASB ? xb[p+480] : 0.f);
        a[5] = make_float2(xa[p+720], HASB ? xb[p+720] : 0.f);
        dft8<-1>(a,b);
        float sv, cv; __sincosf(STEP * (float)p, &sv, &cv);
        float2 w1 = make_float2(cv, sv), w = w1;
        b[1] = cmul(b[1], w);
        #pragma unroll
        for (int u = 2; u < 8; ++u) { w = cmul(w, w1); b[u] = cmul(b[u], w); }
        #pragma unroll
        for (int u = 0; u < 8; ++u) bA[IDX(8*p + u)] = b[u];
    }
}

__device__ __forceinline__ void row_s1_inv(const float2* __restrict__ Zp,
                                           float2* __restrict__ bA, int tid)
{
    constexpr float STEP = PI2 / 1920.0f;
    for (int p = tid; p < 240; p += 256) {
        float2 a[8], b[8];
        #pragma unroll
        for (int t = 0; t < 8; ++t) a[t] = Zp[p + 240*t];
        dft8<1>(a,b);
        float sv, cv; __sincosf(STEP * (float)p, &sv, &cv);
        float2 w1 = make_float2(cv, sv), w = w1;
        b[1] = cmul(b[1], w);
        #pragma unroll
        for (int u = 2; u < 8; ++u) { w = cmul(w, w1); b[u] = cmul(b[u], w); }
        #pragma unroll
        for (int u = 0; u < 8; ++u) bA[IDX(8*p + u)] = b[u];
    }
}

template<int DIR>
__device__ __forceinline__ void row_fin5_store(const float2* __restrict__ src,
                                               float2* __restrict__ gdst, int tid)
{
    for (int q = tid; q < 384; q += 256) {
        float2 a[5], b[5];
        #pragma unroll
        for (int u = 0; u < 5; ++u) a[u] = src[IDX(q + 384*u)];
        dft5<DIR>(a,b);
        #pragma unroll
        for (int u = 0; u < 5; ++u) gdst[q + 384*u] = b[u];
    }
}

// ---------------- kernels ----------------

// K1: row FFTs of padded h. Hrow[r][k], r=0..539 = padded row 270+r.
__global__ __launch_bounds__(256,5) void k_row_fft_h(const float* __restrict__ h,
                                                     float2* __restrict__ Hrow)
{
    __shared__ float2 bA[IDXSZ(1920)], bB[IDXSZ(1920)];
    const int tid = threadIdx.x, r = blockIdx.x;
    row_s1_fwd<false>(h + r*960, nullptr, bA, tid); __syncthreads();
    mid_stage<-1,8,240, 8>(bA, bB, tid); __syncthreads();
    mid_stage<-1,6, 30,64>(bB, bA, tid); __syncthreads();
    row_fin5_store<-1>(bA, Hrow + r*1920, tid);
}

// K2: column FFTs of Hrow (pair/thread, old 6,6,6,5 path) + build KI.
__global__ __launch_bounds__(256,4) void k_col_fft_h_buildK(const float2* __restrict__ Hrow,
                                                            const float* __restrict__ mu1,
                                                            float4* __restrict__ KI)
{
    __shared__ float2 bA[IDXPSZ(2160)], bB[IDXPSZ(2160)];
    const int tid = threadIdx.x;
    const int xcd = blockIdx.x & 7, idx = blockIdx.x >> 3;
    const int cpair = xcd*120 + idx, c0 = cpair*2;
    col_s1_fwd_pair(Hrow, c0, bA, tid);  __syncthreads();
    mid_pair<-1,180, 6>(bA, bB, tid);    __syncthreads();
    mid_pair<-1, 30,36>(bB, bA, tid);    __syncthreads();
    const float sc = mu1[4] / ((1.0f + 1e-6f) * 2073600.0f);
    const float cos0 = __cosf(PI2 * (float)(c0  ) * (1.0f/1920.0f));
    const float cos1 = __cosf(PI2 * (float)(c0+1) * (1.0f/1920.0f));
    float4* Kc = KI + cpair*1080;
    for (int p = tid; p < 216; p += 256) {
        float2 a0[5],a1[5],b0[5],b1[5];
        #pragma unroll
        for (int u = 0; u < 5; ++u) ldp(bA, p + 216*u, a0[u], a1[u]);
        dft5<-1>(a0,b0); dft5<-1>(a1,b1);
        #pragma unroll
        for (int u = 0; u < 5; ++u) {
            const int k = p + 216*u;
            const float cosk = __cosf(PI2 * (float)k * (1.0f/1080.0f));
            float m0 = b0[u].x*b0[u].x + b0[u].y*b0[u].y;
            float m1 = b1[u].x*b1[u].x + b1[u].y*b1[u].y;
            float f0 = sc / (1e-6f*m0 + 1e-5f*(4.0f - 2.0f*cosk - 2.0f*cos0) + 4e-5f);
            float f1 = sc / (1e-6f*m1 + 1e-5f*(4.0f - 2.0f*cosk - 2.0f*cos1) + 4e-5f);
            Kc[k] = make_float4(f0*b0[u].x, -f0*b0[u].y, f1*b1[u].x, -f1*b1[u].y);
        }
    }
}

// K3: row FFTs of padded x, pairs packed z = x_a + i*x_b.
__global__ __launch_bounds__(256,5) void k_row_fft_x(const float* __restrict__ x,
                                                     float2* __restrict__ Z)
{
    __shared__ float2 bA[IDXSZ(1920)], bB[IDXSZ(1920)];
    const int tid = threadIdx.x;
    const int p = blockIdx.x / 540;
    const int r = blockIdx.x % 540;
    row_s1_fwd<true>(x + ((2*p)*540 + r)*960, x + ((2*p+1)*540 + r)*960, bA, tid);
    __syncthreads();
    mid_stage<-1,8,240, 8>(bA, bB, tid); __syncthreads();
    mid_stage<-1,6, 30,64>(bB, bA, tid); __syncthreads();
    row_fin5_store<-1>(bA, Z + (p*540 + r)*1920, tid);
}

// K4: fused column pass, 5 passes / 4 barriers:
// s1(10,global) -> mid12 -> fused9K9 -> mid12 -> fin10+crop(global).
// XCD-chunked swizzle: xcd = bid&7, idx = bid>>3 in [0,480);
// c0 = (xcd*120 + idx%120)*2, plane = idx/120.
__global__ __launch_bounds__(256,4) void k_col_fused(float2* __restrict__ Z,
                                                     const float4* __restrict__ KI)
{
    __shared__ float2 bA[IDXPSZ(2160)], bB[IDXPSZ(2160)];
    const int tid = threadIdx.x;
    const int xcd = blockIdx.x & 7, idx = blockIdx.x >> 3;
    const int pp  = idx / 120;
    const int cpair = xcd*120 + (idx - pp*120), c0 = cpair*2;
    float2* Zp = Z + pp*540*1920;
    col_s1_fwd10_pair(Zp, c0, bA, tid);    __syncthreads();
    mid12_pair<-1,108,10>(bA, bB, tid);    __syncthreads();
    fused9K9_pair(bB, bA, KI, cpair, tid); __syncthreads();
    mid12_pair< 1,120, 9>(bA, bB, tid);    __syncthreads();
    fin10_crop_pair(bB, Zp, c0, tid);
}

// K5: row IFFTs + column crop remap + split pair into two real outputs.
__global__ __launch_bounds__(256,5) void k_row_ifft_out(const float2* __restrict__ Z,
                                                        float* __restrict__ out)
{
    __shared__ float2 bA[IDXSZ(1920)], bB[IDXSZ(1920)];
    const int tid = threadIdx.x;
    const int p = blockIdx.x / 540;
    const int r = blockIdx.x % 540;
    row_s1_inv(Z + (p*540 + r)*1920, bA, tid); __syncthreads();
    mid_stage<1,8,240, 8>(bA, bB, tid); __syncthreads();
    mid_stage<1,6, 30,64>(bB, bA, tid); __syncthreads();
    float* oa = out + ((2*p)*540 + r)*960;
    float* ob = out + ((2*p+1)*540 + r)*960;
    for (int q = tid; q < 384; q += 256) {
        float2 a[5], b[5];
        #pragma unroll
        for (int u = 0; u < 5; ++u) a[u] = bA[IDX(q + 384*u)];
        dft5<1>(a,b);
        oa[q+480] = b[0].x; ob[q+480] = b[0].y;
        if (q < 96)   { oa[q+864] = b[1].x; ob[q+864] = b[1].y; }
        if (q >= 288) { oa[q-288] = b[3].x; ob[q-288] = b[3].y; }
        oa[q+96]  = b[4].x; ob[q+96]  = b[4].y;
    }
}

extern "C" void kernel_launch(void* const* d_in, const int* in_sizes, int n_in,
                              void* d_out, int out_size, void* d_ws, size_t ws_size,
                              hipStream_t stream)
{
    (void)in_sizes; (void)n_in; (void)out_size; (void)ws_size;
    const float* x   = (const float*)d_in[0];
    const float* h   = (const float*)d_in[1];
    const float* mu1 = (const float*)d_in[2];
    float*       out = (float*)d_out;

    // ws layout: KI (960*1080 float4) | Z (4*540*1920 c64); Hrow aliases Z.
    float4* KI   = (float4*)d_ws;
    float2* Z    = (float2*)d_ws + 2*960*1080;
    float2* Hrow = Z;

    k_row_fft_h       <<<540,    256, 0, stream>>>(h, Hrow);
    k_col_fft_h_buildK<<<960,    256, 0, stream>>>(Hrow, mu1, KI);
    k_row_fft_x       <<<4*540,  256, 0, stream>>>(x, Z);
    k_col_fused       <<<3840,   256, 0, stream>>>(Z, KI);
    k_row_ifft_out    <<<4*540,  256, 0, stream>>>(Z, out);
}

// Round 8
// 88.042 us; speedup vs baseline: 1.1514x; 1.1514x over previous
//
#include <hip/hip_runtime.h>

// Le-ADMM reduction: state resets each iteration => output is one linear
// circular filter: out = crop_shift( IFFT2( K . FFT2(pad(x)) ) ),
// K = mu1[4]/((1+1e-6)*FH*FW) * conj(Hp) / (1e-6|Hp|^2 + 1e-5*PsiTPsi + 4e-5).
// Pairs packed z = x_a + i*x_b (K Hermitian => both results real).
//
// R7: R6's high radices REVERTED (90-120 items/pass starved 256 threads:
// VALUBusy 54->40%, K4 44->59us. Rule: items/pass >= ~180). K4 back to the
// R5 schedule (6,6,[5K5],6,6) but run IN-PLACE on a SINGLE LDS buffer:
// each Stockham pass is a permutation, so read-all -> barrier -> write-all
// -> barrier is safe (<=216 items => 1 item/thread, uniform barriers).
// LDS 36.9 -> 18.4KB => 8 blocks/CU (32 waves/CU, was 16); launch_bounds
// (256,8) to force VGPR<=64. K2/rows keep the double-buffer path.
// Keeps: R5 pair-per-thread float4 LDS; R3 XCD-chunked swizzle; stage-1
// from global zero-pad specialized; final stage fused with crop-store.

#define PI2 6.2831853071795864f

__device__ __forceinline__ float2 cadd(float2 a, float2 b){ return make_float2(a.x+b.x, a.y+b.y); }
__device__ __forceinline__ float2 csub(float2 a, float2 b){ return make_float2(a.x-b.x, a.y-b.y); }
__device__ __forceinline__ float2 cmul(float2 a, float2 b){ return make_float2(a.x*b.x - a.y*b.y, a.x*b.y + a.y*b.x); }
__device__ __forceinline__ float4 pk(float2 a, float2 b){ return make_float4(a.x,a.y,b.x,b.y); }

// Row kernels: pad +1 per 16 (b64 access).
__device__ __forceinline__ int IDX(int a){ return a + (a >> 4); }
#define IDXSZ(n) ((n) + ((n) >> 4))
// Column kernels: pad +2 per 32 (keeps even->even so float4 stays aligned).
__device__ __forceinline__ int IDXP(int a){ return a + ((a >> 5) << 1); }
#define IDXPSZ(n) ((n) + (((n) >> 5) << 1) + 4)

// Pair load/store: both columns at per-col position pos.
__device__ __forceinline__ void ldp(const float2* __restrict__ b, int pos,
                                    float2& v0, float2& v1){
    const float4 t = *(const float4*)&b[IDXP(2*pos)];
    v0 = make_float2(t.x,t.y); v1 = make_float2(t.z,t.w);
}
__device__ __forceinline__ void stp(float2* __restrict__ b, int pos,
                                    float2 v0, float2 v1){
    *(float4*)&b[IDXP(2*pos)] = pk(v0, v1);
}

template<int DIR>
__device__ __forceinline__ void dft3(float2 x0, float2 x1, float2 x2,
                                     float2& y0, float2& y1, float2& y2)
{
    constexpr float s3 = (float)DIR * 0.8660254037844386f;
    float2 t = cadd(x1, x2), u = csub(x1, x2);
    float2 m = make_float2(x0.x - 0.5f*t.x, x0.y - 0.5f*t.y);
    float2 iu = make_float2(-s3*u.y, s3*u.x);
    y0 = cadd(x0, t); y1 = cadd(m, iu); y2 = csub(m, iu);
}

template<int DIR>
__device__ __forceinline__ void dft4(float2 a0, float2 a1, float2 a2, float2 a3,
                                     float2& b0, float2& b1, float2& b2, float2& b3)
{
    float2 t0 = cadd(a0,a2), t1 = csub(a0,a2), t2 = cadd(a1,a3), t3 = csub(a1,a3);
    float2 j3 = make_float2(-(float)DIR*t3.y, (float)DIR*t3.x);
    b0 = cadd(t0,t2); b2 = csub(t0,t2); b1 = cadd(t1,j3); b3 = csub(t1,j3);
}

template<int DIR>
__device__ __forceinline__ void dft6(const float2 a[6], float2 b[6])
{
    float2 e0,e1,e2,o0,o1,o2;
    dft3<DIR>(a[0],a[2],a[4], e0,e1,e2);
    dft3<DIR>(a[1],a[3],a[5], o0,o1,o2);
    constexpr float s3 = (float)DIR * 0.8660254037844386f;
    float2 w1 = make_float2( 0.5f, s3);
    float2 w2 = make_float2(-0.5f, s3);
    float2 t1 = cmul(w1,o1), t2 = cmul(w2,o2);
    b[0]=cadd(e0,o0); b[3]=csub(e0,o0);
    b[1]=cadd(e1,t1); b[4]=csub(e1,t1);
    b[2]=cadd(e2,t2); b[5]=csub(e2,t2);
}

template<int DIR>
__device__ __forceinline__ void dft8(const float2 a[8], float2 b[8])
{
    float2 e0,e1,e2,e3,o0,o1,o2,o3;
    dft4<DIR>(a[0],a[2],a[4],a[6], e0,e1,e2,e3);
    dft4<DIR>(a[1],a[3],a[5],a[7], o0,o1,o2,o3);
    constexpr float c = 0.70710678118654752f;
    float2 w1 = make_float2( c, (float)DIR*c);
    float2 w3 = make_float2(-c, (float)DIR*c);
    float2 t1 = cmul(w1,o1);
    float2 t2 = make_float2(-(float)DIR*o2.y, (float)DIR*o2.x);
    float2 t3 = cmul(w3,o3);
    b[0]=cadd(e0,o0); b[4]=csub(e0,o0);
    b[1]=cadd(e1,t1); b[5]=csub(e1,t1);
    b[2]=cadd(e2,t2); b[6]=csub(e2,t2);
    b[3]=cadd(e3,t3); b[7]=csub(e3,t3);
}

template<int DIR>
__device__ __forceinline__ void dft5(const float2 a[5], float2 b[5])
{
    constexpr float C1 = 0.30901699437494742f, S1c = 0.9510565162951535f;
    constexpr float C2 = -0.8090169943749475f, S2c = 0.5877852522924731f;
    float2 t1 = cadd(a[1],a[4]), t2 = cadd(a[2],a[3]), d1 = csub(a[1],a[4]), d2 = csub(a[2],a[3]);
    float2 m1 = make_float2(a[0].x + C1*t1.x + C2*t2.x, a[0].y + C1*t1.y + C2*t2.y);
    float2 m2 = make_float2(a[0].x + C2*t1.x + C1*t2.x, a[0].y + C2*t1.y + C1*t2.y);
    float2 e1 = make_float2(S1c*d1.x + S2c*d2.x, S1c*d1.y + S2c*d2.y);
    float2 e2 = make_float2(S2c*d1.x - S1c*d2.x, S2c*d1.y - S1c*d2.y);
    float2 ie1 = make_float2(-(float)DIR*e1.y, (float)DIR*e1.x);
    float2 ie2 = make_float2(-(float)DIR*e2.y, (float)DIR*e2.x);
    b[0] = make_float2(a[0].x + t1.x + t2.x, a[0].y + t1.y + t2.y);
    b[1] = cadd(m1, ie1); b[4] = csub(m1, ie1);
    b[2] = cadd(m2, ie2); b[3] = csub(m2, ie2);
}

// Generic middle Stockham stage (rows; R = 6 or 8), LDS -> LDS, b64 slots.
template<int DIR, int R, int NCUR, int S>
__device__ __forceinline__ void mid_stage(const float2* __restrict__ src,
                                          float2* __restrict__ dst, int tid)
{
    constexpr int M  = NCUR / R;
    constexpr int NB = M * S;
    constexpr float STEP = (float)DIR * PI2 / (float)NCUR;
    for (int i = tid; i < NB; i += 256) {
        const int p = i / S;
        float2 a[R], b[R];
        #pragma unroll
        for (int t = 0; t < R; ++t) a[t] = src[IDX(i + S*M*t)];
        if constexpr (R == 6) dft6<DIR>(a,b); else dft8<DIR>(a,b);
        float sv, cv; __sincosf(STEP * (float)p, &sv, &cv);
        float2 w1 = make_float2(cv, sv), w = w1;
        b[1] = cmul(b[1], w);
        #pragma unroll
        for (int u = 2; u < R; ++u) { w = cmul(w, w1); b[u] = cmul(b[u], w); }
        const int ob = (i - p*S) + S*(R*p);
        #pragma unroll
        for (int u = 0; u < R; ++u) dst[IDX(ob + S*u)] = b[u];
    }
}

// Column middle stage (K2 path, dbuf), pair-per-thread (R=6).
template<int DIR, int NCUR, int SC>
__device__ __forceinline__ void mid_pair(const float2* __restrict__ src,
                                         float2* __restrict__ dst, int tid)
{
    constexpr int NB = 180;
    constexpr float STEP = (float)DIR * PI2 / (float)NCUR;
    for (int ic = tid; ic < NB; ic += 256) {
        const int p = ic / SC;
        float2 a0[6], a1[6], b0[6], b1[6];
        #pragma unroll
        for (int t = 0; t < 6; ++t) ldp(src, ic + NB*t, a0[t], a1[t]);
        dft6<DIR>(a0,b0); dft6<DIR>(a1,b1);
        float sv, cv; __sincosf(STEP*(float)p, &sv, &cv);
        float2 w1 = make_float2(cv,sv), w = w1;
        b0[1]=cmul(b0[1],w); b1[1]=cmul(b1[1],w);
        #pragma unroll
        for (int u = 2; u < 6; ++u){ w = cmul(w,w1); b0[u]=cmul(b0[u],w); b1[u]=cmul(b1[u],w); }
        const int ob = (ic - p*SC) + SC*6*p;
        #pragma unroll
        for (int u = 0; u < 6; ++u) stp(dst, ob + SC*u, b0[u], b1[u]);
    }
}

// Column middle stage IN-PLACE (K4 path): read-all -> barrier -> write-all
// -> barrier. NB = 180 <= 256 so exactly one item per thread (uniform).
template<int DIR, int NCUR, int SC>
__device__ __forceinline__ void mid_pair_ip(float2* __restrict__ buf, int tid)
{
    constexpr int NB = 180;
    constexpr float STEP = (float)DIR * PI2 / (float)NCUR;
    const bool act = tid < NB;
    float2 b0[6], b1[6]; int ob = 0;
    if (act) {
        const int p = tid / SC;
        float2 a0[6], a1[6];
        #pragma unroll
        for (int t = 0; t < 6; ++t) ldp(buf, tid + NB*t, a0[t], a1[t]);
        dft6<DIR>(a0,b0); dft6<DIR>(a1,b1);
        float sv, cv; __sincosf(STEP*(float)p, &sv, &cv);
        float2 w1 = make_float2(cv,sv), w = w1;
        b0[1]=cmul(b0[1],w); b1[1]=cmul(b1[1],w);
        #pragma unroll
        for (int u = 2; u < 6; ++u){ w = cmul(w,w1); b0[u]=cmul(b0[u],w); b1[u]=cmul(b1[u],w); }
        ob = (tid - p*SC) + SC*6*p;
    }
    __syncthreads();
    if (act) {
        #pragma unroll
        for (int u = 0; u < 6; ++u) stp(buf, ob + SC*u, b0[u], b1[u]);
    }
    __syncthreads();
}

// Column stage 1 (radix-6, SC=1, DIR=-1) from global, pair-per-thread,
// zero-pad: padded rows 270..809 nonzero. Writes only (fresh buffer).
__device__ __forceinline__ void col_s1_fwd_pair(const float2* __restrict__ g, int c0,
                                                float2* __restrict__ bA, int tid)
{
    constexpr float STEP = -PI2 / 1080.0f;
    const float2 z = make_float2(0.f,0.f);
    const float4* gc = (const float4*)(g + c0);
    for (int p = tid; p < 180; p += 256) {
        float2 a0[6], a1[6], b0[6], b1[6];
        a0[0]=a0[5]=a1[0]=a1[5]=z;
        if (p >= 90) { float4 t = gc[(p-90)*960]; a0[1]=make_float2(t.x,t.y); a1[1]=make_float2(t.z,t.w); }
        else         { a0[1]=a1[1]=z; }
        { float4 t = gc[(p+90)*960];  a0[2]=make_float2(t.x,t.y); a1[2]=make_float2(t.z,t.w); }
        { float4 t = gc[(p+270)*960]; a0[3]=make_float2(t.x,t.y); a1[3]=make_float2(t.z,t.w); }
        if (p < 90)  { float4 t = gc[(p+450)*960]; a0[4]=make_float2(t.x,t.y); a1[4]=make_float2(t.z,t.w); }
        else         { a0[4]=a1[4]=z; }
        dft6<-1>(a0,b0); dft6<-1>(a1,b1);
        float sv, cv; __sincosf(STEP*(float)p, &sv, &cv);
        float2 w1 = make_float2(cv,sv), w = w1;
        b0[1]=cmul(b0[1],w); b1[1]=cmul(b1[1],w);
        #pragma unroll
        for (int u = 2; u < 6; ++u){ w = cmul(w,w1); b0[u]=cmul(b0[u],w); b1[u]=cmul(b1[u],w); }
        #pragma unroll
        for (int u = 0; u < 6; ++u) stp(bA, 6*p + u, b0[u], b1[u]);
    }
}

// Fused center IN-PLACE: fwd-final radix-5 (p=0 twiddle-free; spectrum
// k = i+216u) -> *K -> inverse-first radix-5 (twiddle e^{+2pi i p u/1080})
// -> scatter to colpos 5p+u. 216 items, one per thread.
__device__ __forceinline__ void fused5K5_ip(float2* __restrict__ buf,
                                            const float4* __restrict__ KI,
                                            int cpair, int tid)
{
    constexpr float STEP = PI2 / 1080.0f;
    const float4* Kc = KI + cpair*1080;
    const bool act = tid < 216;
    float2 d0[5], d1[5];
    if (act) {
        float2 a0[5],a1[5],s0[5],s1[5];
        #pragma unroll
        for (int u = 0; u < 5; ++u) ldp(buf, tid + 216*u, a0[u], a1[u]);
        dft5<-1>(a0,s0); dft5<-1>(a1,s1);
        #pragma unroll
        for (int u = 0; u < 5; ++u) {
            float4 kk = Kc[tid + 216*u];
            s0[u] = cmul(s0[u], make_float2(kk.x,kk.y));
            s1[u] = cmul(s1[u], make_float2(kk.z,kk.w));
        }
        dft5<1>(s0,d0); dft5<1>(s1,d1);
        float sv, cv; __sincosf(STEP*(float)tid, &sv, &cv);
        float2 w1 = make_float2(cv,sv), w = w1;
        d0[1]=cmul(d0[1],w); d1[1]=cmul(d1[1],w);
        #pragma unroll
        for (int u = 2; u < 5; ++u){ w = cmul(w,w1); d0[u]=cmul(d0[u],w); d1[u]=cmul(d1[u],w); }
    }
    __syncthreads();
    if (act) {
        #pragma unroll
        for (int u = 0; u < 5; ++u) stp(buf, 5*tid + u, d0[u], d1[u]);
    }
    __syncthreads();
}

// Inverse final radix-6 (SC=180, p=0, twiddle-free) fused with crop:
// output n = m + 180u; kept: u=0 (ir=n+270), u=1 if m<90, u=4 if m>=90,
// u=5 (ir=n-810). Reads only; global float4 stores.
__device__ __forceinline__ void fin6_crop_pair(const float2* __restrict__ src,
                                               float2* __restrict__ Zp,
                                               int c0, int tid)
{
    float4* gc = (float4*)(Zp + c0);
    for (int m = tid; m < 180; m += 256) {
        float2 a0[6],a1[6],b0[6],b1[6];
        #pragma unroll
        for (int t = 0; t < 6; ++t) ldp(src, m + 180*t, a0[t], a1[t]);
        dft6<1>(a0,b0); dft6<1>(a1,b1);
        gc[(m+270)*960] = pk(b0[0], b1[0]);
        if (m < 90)  gc[(m+450)*960] = pk(b0[1], b1[1]);
        if (m >= 90) gc[(m-90)*960]  = pk(b0[4], b1[4]);
        gc[(m+90)*960]  = pk(b0[5], b1[5]);
    }
}

// ---------------- row (1920 = 8*8*6*5) pieces (unchanged) ----------------

template<bool HASB>
__device__ __forceinline__ void row_s1_fwd(const float* __restrict__ xa,
                                           const float* __restrict__ xb,
                                           float2* __restrict__ bA, int tid)
{
    constexpr float STEP = -PI2 / 1920.0f;
    const float2 z = make_float2(0.f,0.f);
    for (int p = tid; p < 240; p += 256) {
        float2 a[8], b[8];
        a[0]=z; a[1]=z; a[6]=z; a[7]=z;
        a[2] = make_float2(xa[p],     HASB ? xb[p]     : 0.f);
        a[3] = make_float2(xa[p+240], HASB ? xb[p+240] : 0.f);
        a[4] = make_float2(xa[p+480], HASB ? xb[p+480] : 0.f);
        a[5] = make_float2(xa[p+720], HASB ? xb[p+720] : 0.f);
        dft8<-1>(a,b);
        float sv, cv; __sincosf(STEP * (float)p, &sv, &cv);
        float2 w1 = make_float2(cv, sv), w = w1;
        b[1] = cmul(b[1], w);
        #pragma unroll
        for (int u = 2; u < 8; ++u) { w = cmul(w, w1); b[u] = cmul(b[u], w); }
        #pragma unroll
        for (int u = 0; u < 8; ++u) bA[IDX(8*p + u)] = b[u];
    }
}

__device__ __forceinline__ void row_s1_inv(const float2* __restrict__ Zp,
                                           float2* __restrict__ bA, int tid)
{
    constexpr float STEP = PI2 / 1920.0f;
    for (int p = tid; p < 240; p += 256) {
        float2 a[8], b[8];
        #pragma unroll
        for (int t = 0; t < 8; ++t) a[t] = Zp[p + 240*t];
        dft8<1>(a,b);
        float sv, cv; __sincosf(STEP * (float)p, &sv, &cv);
        float2 w1 = make_float2(cv, sv), w = w1;
        b[1] = cmul(b[1], w);
        #pragma unroll
        for (int u = 2; u < 8; ++u) { w = cmul(w, w1); b[u] = cmul(b[u], w); }
        #pragma unroll
        for (int u = 0; u < 8; ++u) bA[IDX(8*p + u)] = b[u];
    }
}

template<int DIR>
__device__ __forceinline__ void row_fin5_store(const float2* __restrict__ src,
                                               float2* __restrict__ gdst, int tid)
{
    for (int q = tid; q < 384; q += 256) {
        float2 a[5], b[5];
        #pragma unroll
        for (int u = 0; u < 5; ++u) a[u] = src[IDX(q + 384*u)];
        dft5<DIR>(a,b);
        #pragma unroll
        for (int u = 0; u < 5; ++u) gdst[q + 384*u] = b[u];
    }
}

// ---------------- kernels ----------------

// K1: row FFTs of padded h. Hrow[r][k], r=0..539 = padded row 270+r.
__global__ __launch_bounds__(256,5) void k_row_fft_h(const float* __restrict__ h,
                                                     float2* __restrict__ Hrow)
{
    __shared__ float2 bA[IDXSZ(1920)], bB[IDXSZ(1920)];
    const int tid = threadIdx.x, r = blockIdx.x;
    row_s1_fwd<false>(h + r*960, nullptr, bA, tid); __syncthreads();
    mid_stage<-1,8,240, 8>(bA, bB, tid); __syncthreads();
    mid_stage<-1,6, 30,64>(bB, bA, tid); __syncthreads();
    row_fin5_store<-1>(bA, Hrow + r*1920, tid);
}

// K2: column FFTs of Hrow (pair/thread, dbuf) + build pair-interleaved KI.
__global__ __launch_bounds__(256,4) void k_col_fft_h_buildK(const float2* __restrict__ Hrow,
                                                            const float* __restrict__ mu1,
                                                            float4* __restrict__ KI)
{
    __shared__ float2 bA[IDXPSZ(2160)], bB[IDXPSZ(2160)];
    const int tid = threadIdx.x;
    const int xcd = blockIdx.x & 7, idx = blockIdx.x >> 3;
    const int cpair = xcd*120 + idx, c0 = cpair*2;
    col_s1_fwd_pair(Hrow, c0, bA, tid);  __syncthreads();
    mid_pair<-1,180, 6>(bA, bB, tid);    __syncthreads();
    mid_pair<-1, 30,36>(bB, bA, tid);    __syncthreads();
    const float sc = mu1[4] / ((1.0f + 1e-6f) * 2073600.0f);
    const float cos0 = __cosf(PI2 * (float)(c0  ) * (1.0f/1920.0f));
    const float cos1 = __cosf(PI2 * (float)(c0+1) * (1.0f/1920.0f));
    float4* Kc = KI + cpair*1080;
    for (int p = tid; p < 216; p += 256) {
        float2 a0[5],a1[5],b0[5],b1[5];
        #pragma unroll
        for (int u = 0; u < 5; ++u) ldp(bA, p + 216*u, a0[u], a1[u]);
        dft5<-1>(a0,b0); dft5<-1>(a1,b1);
        #pragma unroll
        for (int u = 0; u < 5; ++u) {
            const int k = p + 216*u;
            const float cosk = __cosf(PI2 * (float)k * (1.0f/1080.0f));
            float m0 = b0[u].x*b0[u].x + b0[u].y*b0[u].y;
            float m1 = b1[u].x*b1[u].x + b1[u].y*b1[u].y;
            float f0 = sc / (1e-6f*m0 + 1e-5f*(4.0f - 2.0f*cosk - 2.0f*cos0) + 4e-5f);
            float f1 = sc / (1e-6f*m1 + 1e-5f*(4.0f - 2.0f*cosk - 2.0f*cos1) + 4e-5f);
            Kc[k] = make_float4(f0*b0[u].x, -f0*b0[u].y, f1*b1[u].x, -f1*b1[u].y);
        }
    }
}

// K3: row FFTs of padded x, pairs packed z = x_a + i*x_b.
__global__ __launch_bounds__(256,5) void k_row_fft_x(const float* __restrict__ x,
                                                     float2* __restrict__ Z)
{
    __shared__ float2 bA[IDXSZ(1920)], bB[IDXSZ(1920)];
    const int tid = threadIdx.x;
    const int p = blockIdx.x / 540;
    const int r = blockIdx.x % 540;
    row_s1_fwd<true>(x + ((2*p)*540 + r)*960, x + ((2*p+1)*540 + r)*960, bA, tid);
    __syncthreads();
    mid_stage<-1,8,240, 8>(bA, bB, tid); __syncthreads();
    mid_stage<-1,6, 30,64>(bB, bA, tid); __syncthreads();
    row_fin5_store<-1>(bA, Z + (p*540 + r)*1920, tid);
}

// K4: fused column pass, IN-PLACE single LDS buffer (18.4KB -> 8 blocks/CU).
// s1(6,global) -> mid6 -> mid6 -> fused5K5 -> mid6 -> mid6 -> fin6+crop.
// XCD-chunked swizzle: xcd = bid&7, idx = bid>>3 in [0,480);
// c0 = (xcd*120 + idx%120)*2, plane = idx/120.
__global__ __launch_bounds__(256,8) void k_col_fused(float2* __restrict__ Z,
                                                     const float4* __restrict__ KI)
{
    __shared__ float2 buf[IDXPSZ(2160)];
    const int tid = threadIdx.x;
    const int xcd = blockIdx.x & 7, idx = blockIdx.x >> 3;
    const int pp  = idx / 120;
    const int cpair = xcd*120 + (idx - pp*120), c0 = cpair*2;
    float2* Zp = Z + pp*540*1920;
    col_s1_fwd_pair(Zp, c0, buf, tid);  __syncthreads();
    mid_pair_ip<-1,180, 6>(buf, tid);
    mid_pair_ip<-1, 30,36>(buf, tid);
    fused5K5_ip(buf, KI, cpair, tid);
    mid_pair_ip< 1,216, 5>(buf, tid);
    mid_pair_ip< 1, 36,30>(buf, tid);
    fin6_crop_pair(buf, Zp, c0, tid);
}

// K5: row IFFTs + column crop remap + split pair into two real outputs.
__global__ __launch_bounds__(256,5) void k_row_ifft_out(const float2* __restrict__ Z,
                                                        float* __restrict__ out)
{
    __shared__ float2 bA[IDXSZ(1920)], bB[IDXSZ(1920)];
    const int tid = threadIdx.x;
    const int p = blockIdx.x / 540;
    const int r = blockIdx.x % 540;
    row_s1_inv(Z + (p*540 + r)*1920, bA, tid); __syncthreads();
    mid_stage<1,8,240, 8>(bA, bB, tid); __syncthreads();
    mid_stage<1,6, 30,64>(bB, bA, tid); __syncthreads();
    float* oa = out + ((2*p)*540 + r)*960;
    float* ob = out + ((2*p+1)*540 + r)*960;
    for (int q = tid; q < 384; q += 256) {
        float2 a[5], b[5];
        #pragma unroll
        for (int u = 0; u < 5; ++u) a[u] = bA[IDX(q + 384*u)];
        dft5<1>(a,b);
        oa[q+480] = b[0].x; ob[q+480] = b[0].y;
        if (q < 96)   { oa[q+864] = b[1].x; ob[q+864] = b[1].y; }
        if (q >= 288) { oa[q-288] = b[3].x; ob[q-288] = b[3].y; }
        oa[q+96]  = b[4].x; ob[q+96]  = b[4].y;
    }
}

extern "C" void kernel_launch(void* const* d_in, const int* in_sizes, int n_in,
                              void* d_out, int out_size, void* d_ws, size_t ws_size,
                              hipStream_t stream)
{
    (void)in_sizes; (void)n_in; (void)out_size; (void)ws_size;
    const float* x   = (const float*)d_in[0];
    const float* h   = (const float*)d_in[1];
    const float* mu1 = (const float*)d_in[2];
    float*       out = (float*)d_out;

    // ws layout: KI (960*1080 float4) | Z (4*540*1920 c64); Hrow aliases Z.
    float4* KI   = (float4*)d_ws;
    float2* Z    = (float2*)d_ws + 2*960*1080;
    float2* Hrow = Z;

    k_row_fft_h       <<<540,    256, 0, stream>>>(h, Hrow);
    k_col_fft_h_buildK<<<960,    256, 0, stream>>>(Hrow, mu1, KI);
    k_row_fft_x       <<<4*540,  256, 0, stream>>>(x, Z);
    k_col_fused       <<<3840,   256, 0, stream>>>(Z, KI);
    k_row_ifft_out    <<<4*540,  256, 0, stream>>>(Z, out);
}